// Round 7
// baseline (273.880 us; speedup 1.0000x reference)
//
#include <hip/hip_runtime.h>
#include <stdint.h>

typedef __bf16 bf16;
typedef __bf16 bf16x4 __attribute__((ext_vector_type(4)));
typedef __bf16 bf16x8 __attribute__((ext_vector_type(8)));
typedef float f32x4 __attribute__((ext_vector_type(4)));
typedef short short4v __attribute__((ext_vector_type(4)));

#define NB 4
#define NS 2048
#define ND 1024
#define NH 16
#define NHD 64
#define QSCALE 0.1803368801111204f   // 0.125 * log2(e): scores in log2 domain
#define FMAX   8.0f                  // fixed softmax shift (log2 domain)

typedef const __attribute__((address_space(1))) unsigned GU;
typedef __attribute__((address_space(3))) unsigned LU;

#define WAIT_VM(n) asm volatile("s_waitcnt vmcnt(" #n ")" ::: "memory")
#define BAR() do { asm volatile("" ::: "memory"); __builtin_amdgcn_s_barrier(); \
                   asm volatile("" ::: "memory"); } while (0)

__device__ __forceinline__ bf16x8 load8f(const float* p) {
    float4 a = *(const float4*)p;
    float4 b = *(const float4*)(p + 4);
    bf16x8 r;
    r[0] = (bf16)a.x; r[1] = (bf16)a.y; r[2] = (bf16)a.z; r[3] = (bf16)a.w;
    r[4] = (bf16)b.x; r[5] = (bf16)b.y; r[6] = (bf16)b.z; r[7] = (bf16)b.w;
    return r;
}
__device__ __forceinline__ void store8(bf16* p, bf16x8 v) { *(bf16x8*)p = v; }
__device__ __forceinline__ void store8(float* p, bf16x8 v) {
    float4 a; a.x = (float)v[0]; a.y = (float)v[1]; a.z = (float)v[2]; a.w = (float)v[3];
    float4 b; b.x = (float)v[4]; b.y = (float)v[5]; b.z = (float)v[6]; b.w = (float)v[7];
    *(float4*)p = a; *(float4*)(p + 4) = b;
}

// 16x16x16 bf16 MFMA (K=16): A/B frags are 4 bf16/lane, k = quad*4+j.
__device__ __forceinline__ f32x4 mfma16(bf16x4 a, bf16x4 b, f32x4 c) {
#ifdef __HIP_DEVICE_COMPILE__
#if __has_builtin(__builtin_amdgcn_mfma_f32_16x16x16bf16_1k)
    return __builtin_amdgcn_mfma_f32_16x16x16bf16_1k(
        __builtin_bit_cast(short4v, a), __builtin_bit_cast(short4v, b), c, 0, 0, 0);
#else
    f32x4 d;
    asm("v_mfma_f32_16x16x16_bf16 %0, %1, %2, %3"
        : "=v"(d) : "v"(a), "v"(b), "v"(c));
    return d;
#endif
#else
    return c;  // host stub, never executed
#endif
}

// attn LDS swizzle: XOR col by quad-of-row*16; preserves >=4-elem contiguity.
__device__ __forceinline__ int sw(int row, int col) {
    return row * 72 + (col ^ (((row >> 2) & 3) * 16));
}

// One-shot fp32 -> bf16 conversion of x, Wqkv, Wproj (biases stay fp32).
__global__ __launch_bounds__(256)
void convert_kernel(const float* __restrict__ s0, bf16* __restrict__ d0, int n0,
                    const float* __restrict__ s1, bf16* __restrict__ d1, int n1,
                    const float* __restrict__ s2, bf16* __restrict__ d2, int n2)
{
    int idx = (blockIdx.x * 256 + threadIdx.x) * 8;
    const float* s; bf16* d;
    if (idx < n0)              { s = s0 + idx;  d = d0 + idx; }
    else if ((idx -= n0) < n1) { s = s1 + idx;  d = d1 + idx; }
    else if ((idx -= n1) < n2) { s = s2 + idx;  d = d2 + idx; }
    else return;
    *(bf16x8*)d = load8f(s);
}

// ---------------- 128x256-tile GEMM, BK=64, 2-phase counted-vmcnt -----------
// Proven structure (round 4: QKV 73us, 704 TF, conflicts 2e5).  8-phase port
// (rounds 5-6) measured WORSE at this shape (K=1024, 16 tiles) -- reverted.
template<typename TO, int MODE>
__device__ __forceinline__ void epi256(
    f32x4 (&acc)[4][4], bf16* Ls, const float* __restrict__ bias,
    TO* __restrict__ O0, bf16* __restrict__ O1, bf16* __restrict__ O2,
    int N, int m0, int n0, int tid)
{
    const int lane = tid & 63;
    const int w = tid >> 6, wm = w >> 2, wn = w & 3;
    const int lr = lane & 15, quad = lane >> 4;
    const int cls = (MODE == 0) ? (n0 >> 10) : 1;

    if (MODE == 0 && cls == 2) {
        // V: stage transposed CT[col 256][row 128 + 8 pad], coalesced along S
#pragma unroll
        for (int im = 0; im < 4; ++im) {
            int rowb = wm * 64 + im * 16 + quad * 4;
#pragma unroll
            for (int in = 0; in < 4; ++in) {
                int col = wn * 64 + in * 16 + lr;
                float bv = bias[n0 + col];
                bf16x4 pv;
#pragma unroll
                for (int r = 0; r < 4; ++r) pv[r] = (bf16)(acc[im][in][r] + bv);
                *(bf16x4*)&Ls[col * 136 + rowb] = pv;
            }
        }
        __syncthreads();
        const int b = m0 >> 11, s0 = m0 & 2047;
#pragma unroll
        for (int p = 0; p < 8; ++p) {
            int idx = tid + 512 * p;
            int col = idx >> 4, mg = idx & 15;
            bf16x8 v8 = *(const bf16x8*)&Ls[col * 136 + mg * 8];
            int ncol = n0 + col;
            int h = (ncol >> 6) & 15, hd = ncol & 63;
            *(bf16x8*)&((bf16*)O0)[((size_t)(b * NH + h) * NHD + hd) * NS + s0 + mg * 8] = v8;
        }
    } else {
#pragma unroll
        for (int im = 0; im < 4; ++im) {
            int rowb = wm * 64 + im * 16 + quad * 4;
#pragma unroll
            for (int in = 0; in < 4; ++in) {
                int col = wn * 64 + in * 16 + lr;
                float bv = bias[n0 + col];
#pragma unroll
                for (int r = 0; r < 4; ++r) {
                    float v = acc[im][in][r] + bv;
                    if (MODE == 0 && cls == 0) v *= QSCALE;
                    Ls[(rowb + r) * 264 + col] = (bf16)v;
                }
            }
        }
        __syncthreads();
#pragma unroll
        for (int p = 0; p < 8; ++p) {
            int idx = tid + 512 * p;
            int row = idx >> 5, colg = (idx & 31) * 8;
            bf16x8 v8 = *(const bf16x8*)&Ls[row * 264 + colg];
            if (MODE == 0) {
                int ncol = n0 + colg;
                int h = (ncol >> 6) & 15, hd = ncol & 63;
                int m = m0 + row, b = m >> 11, s = m & 2047;
                bf16* dst = (cls == 0) ? O1 : O2;
                *(bf16x8*)&dst[((size_t)(b * NH + h) * NS + s) * NHD + hd] = v8;
            } else {
                store8(&O0[(size_t)(m0 + row) * N + n0 + colg], v8);
            }
        }
    }
}

template<typename TO, int MODE>
__global__ __launch_bounds__(512, 2)
void gemm256(const bf16* __restrict__ Xp, const bf16* __restrict__ Wp,
             const float* __restrict__ bias, TO* __restrict__ O0,
             bf16* __restrict__ O1, bf16* __restrict__ O2, int N, int K)
{
    __shared__ __align__(16) bf16 L[49152];   // 96KB: dbuf d at d*24576 elems
    const int tid  = threadIdx.x;
    const int lane = tid & 63;
    const int w    = tid >> 6;
    const int lr   = lane & 15, quad = lane >> 4;
    const int wm   = w >> 2, wn = w & 3;
    const int m0   = blockIdx.y * 128;
    const int n0   = blockIdx.x * 256;

    // LDS dest linear (gload_lds); swizzled content via inverse-permuted
    // per-lane global source: lane' = lane ^ ((lane>>3)&7).
    const int lanep = lane ^ ((lane >> 3) & 7);
    const bf16* gsrc[6]; int ldst[6];
#pragma unroll
    for (int j = 0; j < 6; ++j) {
        int g = w * 6 + j;
        int isA = g < 16;
        int gb = isA ? g : g - 16;
        int c = gb * 64 + lanep;
        int grow = c >> 3, gcol = (c & 7) * 8;
        gsrc[j] = (isA ? Xp + (size_t)(m0 + grow) * K
                       : Wp + (size_t)(n0 + grow) * K) + gcol;
        ldst[j] = (isA ? 0 : 8192) + gb * 512;
    }

#define STAGE256(t) do { const int kofs_ = (t) * 64;                           \
    bf16* Lb_ = &L[((t) & 1) * 24576];                                         \
    _Pragma("unroll")                                                          \
    for (int j = 0; j < 6; ++j)                                                \
        __builtin_amdgcn_global_load_lds((GU*)(gsrc[j] + kofs_),               \
                                         (LU*)&Lb_[ldst[j]], 16, 0, 0); } while (0)

    // fragment reads: row base + 3-bit XOR-swizzled column (incl. ks bit)
    const int cxor = (lr & 7) * 8;
    const int col0 = (0 * 32 + quad * 8) ^ cxor;
    const int col1 = (1 * 32 + quad * 8) ^ cxor;
    const int arow0 = (wm * 64 + lr) * 64;
    const int brow0 = 8192 + (wn * 64 + lr) * 64;

    f32x4 acc[4][4] = {};
    const int NT = K >> 6;

    STAGE256(0);
    STAGE256(1);
    WAIT_VM(6);
    BAR();

    for (int t = 0; t < NT; ++t) {
        const int db = (t & 1) * 24576;
        bf16x8 afr[2][4], bfr[2][4];
#pragma unroll
        for (int i = 0; i < 4; ++i) {
            afr[0][i] = *(const bf16x8*)&L[db + arow0 + i * 1024 + col0];
            afr[1][i] = *(const bf16x8*)&L[db + arow0 + i * 1024 + col1];
            bfr[0][i] = *(const bf16x8*)&L[db + brow0 + i * 1024 + col0];
            bfr[1][i] = *(const bf16x8*)&L[db + brow0 + i * 1024 + col1];
        }
        __builtin_amdgcn_s_setprio(1);
#pragma unroll
        for (int ks = 0; ks < 2; ++ks)
#pragma unroll
            for (int im = 0; im < 4; ++im)
#pragma unroll
                for (int in = 0; in < 4; ++in)
                    acc[im][in] = __builtin_amdgcn_mfma_f32_16x16x32_bf16(
                        afr[ks][im], bfr[ks][in], acc[im][in], 0, 0, 0);
        __builtin_amdgcn_s_setprio(0);
        BAR();
        if (t + 2 < NT) { STAGE256(t + 2); WAIT_VM(6); }
        else WAIT_VM(0);
        BAR();
    }

    epi256<TO, MODE>(acc, L, bias, O0, O1, O2, N, m0, n0, tid);
}
#undef STAGE256

// Flash attention, causal, fixed-shift log2 softmax, P kept in REGISTERS.
// v4: 256 q-rows/block, 64/wave (4 q-groups).  K/V fragments are
// wave-invariant: one K-frag / V-frag read now feeds FOUR q-groups ->
// LDS bytes per FLOP halves again vs v3; MFMA per tile doubles (hides T14
// staging); total K/V staging traffic halves (8 jt-blocks/bh, was 16).
// Grid 512 = exactly 2 blocks/CU; VGPR ~200 -> 2 waves/SIMD.
__global__ __launch_bounds__(256, 2)
void attn_kernel(const bf16* __restrict__ Q, const bf16* __restrict__ K,
                 const bf16* __restrict__ Vt_g, bf16* __restrict__ ctx)
{
    const int jt = 7 - (blockIdx.x >> 6);    // Q-tile index (256 rows), heavy first
    const int bh = blockIdx.x & 63;
    const int b  = bh >> 4, h = bh & 15;
    const int q0 = jt * 256;
    const bf16* Qp = Q + (size_t)bh * NS * NHD;
    const bf16* Kp = K + (size_t)bh * NS * NHD;
    const bf16* Vp = Vt_g + (size_t)bh * NHD * NS;   // [hd][S]

    // Q staging (256x72 = 36KB) aliases onto Kh+Vh (18KB) + O staging at end.
    __shared__ union {
        struct { bf16 Kh[64 * 72]; bf16 Vh[64 * 72]; } s;
        bf16 QO[256 * 72];
    } u;

    const int tid  = threadIdx.x;
    const int lane = tid & 63;
    const int w    = tid >> 6;
    const int lr   = lane & 15, quad = lane >> 4;

    const int srow = tid >> 3;          // 0..31
    const int sch  = (tid & 7) * 8;

    // T14 prefetch registers: K/V tile in flight during compute
    bf16x8 kreg[2], vreg[2];
#pragma unroll
    for (int i = 0; i < 2; ++i) {
        kreg[i] = *(const bf16x8*)(Kp + (size_t)(srow + 32 * i) * NHD + sch);
        vreg[i] = *(const bf16x8*)(Vp + (size_t)(srow + 32 * i) * NS + sch);
    }

    // stage Q (256 rows) while the kt=0 K/V loads are in flight
#pragma unroll
    for (int i = 0; i < 8; ++i) {
        int row = srow + 32 * i;
        *(bf16x8*)(&u.QO[sw(row, sch)]) =
            *(const bf16x8*)(Qp + (size_t)(q0 + row) * NHD + sch);
    }
    __syncthreads();

    // hoist Q-fragments (k-loop invariant): qf[qg][ks], 64 rows per wave
    bf16x8 qf[4][2];
#pragma unroll
    for (int qg = 0; qg < 4; ++qg)
#pragma unroll
        for (int ks = 0; ks < 2; ++ks)
            qf[qg][ks] = *(const bf16x8*)(&u.QO[sw(w * 64 + qg * 16 + lr, ks * 32 + quad * 8)]);
    __syncthreads();   // QO region dead; Kh/Vh writes may begin

    float l_part[4] = {0.f, 0.f, 0.f, 0.f};
    f32x4 acco[4][4] = {};           // O^T per qg: hd = jn*16+quad*4+r, col = q

    const int wq0 = q0 + w * 64;     // this wave's first q row
    const int nkt = 4 * jt + 4;
    for (int kt = 0; kt < nkt; ++kt) {
        // reg -> LDS (waits vmcnt for this tile's loads via register dep)
#pragma unroll
        for (int i = 0; i < 2; ++i) {
            *(bf16x8*)(&u.s.Kh[sw(srow + 32 * i, sch)]) = kreg[i];
            *(bf16x8*)(&u.s.Vh[sw(srow + 32 * i, sch)]) = vreg[i];
        }
        // issue next tile's global loads; land during compute below
        if (kt + 1 < nkt) {
#pragma unroll
            for (int i = 0; i < 2; ++i) {
                kreg[i] = *(const bf16x8*)(Kp + (size_t)((kt + 1) * 64 + srow + 32 * i) * NHD + sch);
                vreg[i] = *(const bf16x8*)(Vp + (size_t)(srow + 32 * i) * NS + (kt + 1) * 64 + sch);
            }
        }
        __syncthreads();   // LDS tile kt ready

        if (kt * 64 <= wq0 + 63) {
            // S^T = K @ Q^T: one K-frag read feeds FOUR q-groups
            f32x4 sacc[4][4] = {};
#pragma unroll
            for (int ks = 0; ks < 2; ++ks) {
#pragma unroll
                for (int kn = 0; kn < 4; ++kn) {
                    bf16x8 ak = *(const bf16x8*)(&u.s.Kh[sw(kn * 16 + lr, ks * 32 + quad * 8)]);
#pragma unroll
                    for (int qg = 0; qg < 4; ++qg)
                        sacc[qg][kn] = __builtin_amdgcn_mfma_f32_16x16x32_bf16(
                            ak, qf[qg][ks], sacc[qg][kn], 0, 0, 0);
                }
            }

            // softmax in registers; p-values land directly in x16 B-frag layout
            const bool diag = (kt * 64 + 63 > wq0);
            bf16x4 pf[4][4];
#pragma unroll
            for (int qg = 0; qg < 4; ++qg) {
                const int qrow = wq0 + qg * 16 + lr;
#pragma unroll
                for (int kn = 0; kn < 4; ++kn) {
#pragma unroll
                    for (int r = 0; r < 4; ++r) {
                        float x = sacc[qg][kn][r];
                        if (diag) {
                            int kcol = kt * 64 + kn * 16 + quad * 4 + r;
                            x = (kcol <= qrow) ? x : -INFINITY;
                        }
                        float p = __builtin_amdgcn_exp2f(x - FMAX);  // -inf -> 0
                        l_part[qg] += p;
                        pf[qg][kn][r] = (bf16)p;
                    }
                }
            }

            // O^T += V^T @ P^T: one V-frag read feeds FOUR q-groups
#pragma unroll
            for (int kn = 0; kn < 4; ++kn) {
#pragma unroll
                for (int jn = 0; jn < 4; ++jn) {
                    bf16x4 av = *(const bf16x4*)(&u.s.Vh[sw(jn * 16 + lr, kn * 16 + quad * 4)]);
#pragma unroll
                    for (int qg = 0; qg < 4; ++qg)
                        acco[qg][jn] = mfma16(av, pf[qg][kn], acco[qg][jn]);
                }
            }
        }
        __syncthreads();   // all reads done before next tile's LDS write
    }

    // l lives per-lane (one qrow per lane per qg); reduce across the 4 quads
    float rinv[4];
#pragma unroll
    for (int qg = 0; qg < 4; ++qg) {
        float l = l_part[qg];
        l += __shfl_xor(l, 16);
        l += __shfl_xor(l, 32);
        rinv[qg] = 1.0f / l;
    }

    // epilogue: O^T -> QO (dead) as packed b64 rows, then coalesced b128 out
    __syncthreads();
#pragma unroll
    for (int qg = 0; qg < 4; ++qg)
#pragma unroll
        for (int jn = 0; jn < 4; ++jn) {
            bf16x4 pv;
#pragma unroll
            for (int r = 0; r < 4; ++r) pv[r] = (bf16)(acco[qg][jn][r] * rinv[qg]);
            *(bf16x4*)&u.QO[(w * 64 + qg * 16 + lr) * 72 + jn * 16 + quad * 4] = pv;
        }
    __syncthreads();
#pragma unroll
    for (int p = 0; p < 8; ++p) {
        int idx = tid + 256 * p;
        int row = idx >> 3, colg = (idx & 7) * 8;
        bf16x8 v8 = *(const bf16x8*)&u.QO[row * 72 + colg];
        *(bf16x8*)&ctx[((size_t)(b * NS) + q0 + row) * ND + h * NHD + colg] = v8;
    }
}

extern "C" void kernel_launch(void* const* d_in, const int* in_sizes, int n_in,
                              void* d_out, int out_size, void* d_ws, size_t ws_size,
                              hipStream_t stream) {
    const float* x     = (const float*)d_in[0];
    const float* Wqkv  = (const float*)d_in[1];
    const float* bqkv  = (const float*)d_in[2];
    const float* Wproj = (const float*)d_in[3];
    const float* bproj = (const float*)d_in[4];
    float* out = (float*)d_out;

    const size_t per = (size_t)NB * NH * NS * NHD;  // 8,388,608 elems
    bf16* q_ws = (bf16*)d_ws;
    bf16* k_ws = q_ws + per;
    bf16* v_ws = k_ws + per;        // V transposed [B,H,HD,S]
    bf16* x_bf = v_ws + per;        // x as bf16; reused as ctx after QKV GEMM
    bf16* c_ws = x_bf;              // alias: x_bf dead once QKV GEMM completes
    bf16* wq_bf = x_bf + per;       // Wqkv bf16
    bf16* wp_bf = wq_bf + (size_t)3 * ND * ND;  // Wproj bf16

    const int n0 = NB * NS * ND;        // 8,388,608
    const int n1 = 3 * ND * ND;         // 3,145,728
    const int n2 = ND * ND;             // 1,048,576
    convert_kernel<<<(n0 + n1 + n2) / (256 * 8), 256, 0, stream>>>(
        x, x_bf, n0, Wqkv, wq_bf, n1, Wproj, wp_bf, n2);

    // QKV: 128x256 tiles -> grid 12x64 = 768 blocks = 3/CU (proven 2-phase)
    dim3 gq(3 * ND / 256, NB * NS / 128);
    gemm256<bf16, 0><<<gq, 512, 0, stream>>>(
        x_bf, wq_bf, bqkv, v_ws, q_ws, k_ws, 3 * ND, ND);

    // attn: 256 q-rows/block -> 8 jt x 64 bh = 512 blocks = 2/CU
    attn_kernel<<<dim3(NB * NH * 8), 256, 0, stream>>>(q_ws, k_ws, v_ws, c_ws);

    // proj: 128x256 tiles -> grid 4x64 = 256 blocks = exactly 1/CU (2-phase)
    dim3 gp(ND / 256, NB * NS / 128);
    gemm256<float, 1><<<gp, 512, 0, stream>>>(
        c_ws, wp_bf, bproj, out, nullptr, nullptr, ND, ND);
}

// Round 8
// 262.031 us; speedup vs baseline: 1.0452x; 1.0452x over previous
//
#include <hip/hip_runtime.h>
#include <stdint.h>

typedef __bf16 bf16;
typedef __bf16 bf16x4 __attribute__((ext_vector_type(4)));
typedef __bf16 bf16x8 __attribute__((ext_vector_type(8)));
typedef float f32x4 __attribute__((ext_vector_type(4)));
typedef short short4v __attribute__((ext_vector_type(4)));

#define NB 4
#define NS 2048
#define ND 1024
#define NH 16
#define NHD 64
#define QSCALE 0.1803368801111204f   // 0.125 * log2(e): scores in log2 domain
#define FMAX   8.0f                  // fixed softmax shift (log2 domain)

typedef const __attribute__((address_space(1))) unsigned GU;
typedef __attribute__((address_space(3))) unsigned LU;

#define WAIT_VM(n) asm volatile("s_waitcnt vmcnt(" #n ")" ::: "memory")
#define BAR() do { asm volatile("" ::: "memory"); __builtin_amdgcn_s_barrier(); \
                   asm volatile("" ::: "memory"); } while (0)

__device__ __forceinline__ bf16x8 load8f(const float* p) {
    float4 a = *(const float4*)p;
    float4 b = *(const float4*)(p + 4);
    bf16x8 r;
    r[0] = (bf16)a.x; r[1] = (bf16)a.y; r[2] = (bf16)a.z; r[3] = (bf16)a.w;
    r[4] = (bf16)b.x; r[5] = (bf16)b.y; r[6] = (bf16)b.z; r[7] = (bf16)b.w;
    return r;
}
__device__ __forceinline__ void store8(bf16* p, bf16x8 v) { *(bf16x8*)p = v; }
__device__ __forceinline__ void store8(float* p, bf16x8 v) {
    float4 a; a.x = (float)v[0]; a.y = (float)v[1]; a.z = (float)v[2]; a.w = (float)v[3];
    float4 b; b.x = (float)v[4]; b.y = (float)v[5]; b.z = (float)v[6]; b.w = (float)v[7];
    *(float4*)p = a; *(float4*)(p + 4) = b;
}

// 16x16x16 bf16 MFMA (K=16): A/B frags are 4 bf16/lane, k = quad*4+j.
__device__ __forceinline__ f32x4 mfma16(bf16x4 a, bf16x4 b, f32x4 c) {
#ifdef __HIP_DEVICE_COMPILE__
#if __has_builtin(__builtin_amdgcn_mfma_f32_16x16x16bf16_1k)
    return __builtin_amdgcn_mfma_f32_16x16x16bf16_1k(
        __builtin_bit_cast(short4v, a), __builtin_bit_cast(short4v, b), c, 0, 0, 0);
#else
    f32x4 d;
    asm("v_mfma_f32_16x16x16_bf16 %0, %1, %2, %3"
        : "=v"(d) : "v"(a), "v"(b), "v"(c));
    return d;
#endif
#else
    return c;  // host stub, never executed
#endif
}

// attn LDS swizzle: XOR col by quad-of-row*16; preserves >=4-elem contiguity.
__device__ __forceinline__ int sw(int row, int col) {
    return row * 72 + (col ^ (((row >> 2) & 3) * 16));
}

// One-shot fp32 -> bf16 conversion of x, Wqkv, Wproj (biases stay fp32).
__global__ __launch_bounds__(256)
void convert_kernel(const float* __restrict__ s0, bf16* __restrict__ d0, int n0,
                    const float* __restrict__ s1, bf16* __restrict__ d1, int n1,
                    const float* __restrict__ s2, bf16* __restrict__ d2, int n2)
{
    int idx = (blockIdx.x * 256 + threadIdx.x) * 8;
    const float* s; bf16* d;
    if (idx < n0)              { s = s0 + idx;  d = d0 + idx; }
    else if ((idx -= n0) < n1) { s = s1 + idx;  d = d1 + idx; }
    else if ((idx -= n1) < n2) { s = s2 + idx;  d = d2 + idx; }
    else return;
    *(bf16x8*)d = load8f(s);
}

// ---------------- 128x256-tile GEMM, BK=64, 2-phase counted-vmcnt -----------
// Proven structure (round 4: QKV 73us, 704 TF, conflicts 2e5).  8-phase port
// (rounds 5-6) measured WORSE at this shape (K=1024, 16 tiles) -- reverted.
template<typename TO, int MODE>
__device__ __forceinline__ void epi256(
    f32x4 (&acc)[4][4], bf16* Ls, const float* __restrict__ bias,
    TO* __restrict__ O0, bf16* __restrict__ O1, bf16* __restrict__ O2,
    int N, int m0, int n0, int tid)
{
    const int lane = tid & 63;
    const int w = tid >> 6, wm = w >> 2, wn = w & 3;
    const int lr = lane & 15, quad = lane >> 4;
    const int cls = (MODE == 0) ? (n0 >> 10) : 1;

    if (MODE == 0 && cls == 2) {
        // V: stage transposed CT[col 256][row 128 + 8 pad], coalesced along S
#pragma unroll
        for (int im = 0; im < 4; ++im) {
            int rowb = wm * 64 + im * 16 + quad * 4;
#pragma unroll
            for (int in = 0; in < 4; ++in) {
                int col = wn * 64 + in * 16 + lr;
                float bv = bias[n0 + col];
                bf16x4 pv;
#pragma unroll
                for (int r = 0; r < 4; ++r) pv[r] = (bf16)(acc[im][in][r] + bv);
                *(bf16x4*)&Ls[col * 136 + rowb] = pv;
            }
        }
        __syncthreads();
        const int b = m0 >> 11, s0 = m0 & 2047;
#pragma unroll
        for (int p = 0; p < 8; ++p) {
            int idx = tid + 512 * p;
            int col = idx >> 4, mg = idx & 15;
            bf16x8 v8 = *(const bf16x8*)&Ls[col * 136 + mg * 8];
            int ncol = n0 + col;
            int h = (ncol >> 6) & 15, hd = ncol & 63;
            *(bf16x8*)&((bf16*)O0)[((size_t)(b * NH + h) * NHD + hd) * NS + s0 + mg * 8] = v8;
        }
    } else {
#pragma unroll
        for (int im = 0; im < 4; ++im) {
            int rowb = wm * 64 + im * 16 + quad * 4;
#pragma unroll
            for (int in = 0; in < 4; ++in) {
                int col = wn * 64 + in * 16 + lr;
                float bv = bias[n0 + col];
#pragma unroll
                for (int r = 0; r < 4; ++r) {
                    float v = acc[im][in][r] + bv;
                    if (MODE == 0 && cls == 0) v *= QSCALE;
                    Ls[(rowb + r) * 264 + col] = (bf16)v;
                }
            }
        }
        __syncthreads();
#pragma unroll
        for (int p = 0; p < 8; ++p) {
            int idx = tid + 512 * p;
            int row = idx >> 5, colg = (idx & 31) * 8;
            bf16x8 v8 = *(const bf16x8*)&Ls[row * 264 + colg];
            if (MODE == 0) {
                int ncol = n0 + colg;
                int h = (ncol >> 6) & 15, hd = ncol & 63;
                int m = m0 + row, b = m >> 11, s = m & 2047;
                bf16* dst = (cls == 0) ? O1 : O2;
                *(bf16x8*)&dst[((size_t)(b * NH + h) * NS + s) * NHD + hd] = v8;
            } else {
                store8(&O0[(size_t)(m0 + row) * N + n0 + colg], v8);
            }
        }
    }
}

template<typename TO, int MODE>
__global__ __launch_bounds__(512, 2)
void gemm256(const bf16* __restrict__ Xp, const bf16* __restrict__ Wp,
             const float* __restrict__ bias, TO* __restrict__ O0,
             bf16* __restrict__ O1, bf16* __restrict__ O2, int N, int K)
{
    __shared__ __align__(16) bf16 L[49152];   // 96KB: dbuf d at d*24576 elems
    const int tid  = threadIdx.x;
    const int lane = tid & 63;
    const int w    = tid >> 6;
    const int lr   = lane & 15, quad = lane >> 4;
    const int wm   = w >> 2, wn = w & 3;
    const int m0   = blockIdx.y * 128;
    const int n0   = blockIdx.x * 256;

    // LDS dest linear (gload_lds); swizzled content via inverse-permuted
    // per-lane global source: lane' = lane ^ ((lane>>3)&7).
    const int lanep = lane ^ ((lane >> 3) & 7);
    const bf16* gsrc[6]; int ldst[6];
#pragma unroll
    for (int j = 0; j < 6; ++j) {
        int g = w * 6 + j;
        int isA = g < 16;
        int gb = isA ? g : g - 16;
        int c = gb * 64 + lanep;
        int grow = c >> 3, gcol = (c & 7) * 8;
        gsrc[j] = (isA ? Xp + (size_t)(m0 + grow) * K
                       : Wp + (size_t)(n0 + grow) * K) + gcol;
        ldst[j] = (isA ? 0 : 8192) + gb * 512;
    }

#define STAGE256(t) do { const int kofs_ = (t) * 64;                           \
    bf16* Lb_ = &L[((t) & 1) * 24576];                                         \
    _Pragma("unroll")                                                          \
    for (int j = 0; j < 6; ++j)                                                \
        __builtin_amdgcn_global_load_lds((GU*)(gsrc[j] + kofs_),               \
                                         (LU*)&Lb_[ldst[j]], 16, 0, 0); } while (0)

    // fragment reads: row base + 3-bit XOR-swizzled column (incl. ks bit)
    const int cxor = (lr & 7) * 8;
    const int col0 = (0 * 32 + quad * 8) ^ cxor;
    const int col1 = (1 * 32 + quad * 8) ^ cxor;
    const int arow0 = (wm * 64 + lr) * 64;
    const int brow0 = 8192 + (wn * 64 + lr) * 64;

    f32x4 acc[4][4] = {};
    const int NT = K >> 6;

    STAGE256(0);
    STAGE256(1);
    WAIT_VM(6);
    BAR();

    for (int t = 0; t < NT; ++t) {
        const int db = (t & 1) * 24576;
        bf16x8 afr[2][4], bfr[2][4];
#pragma unroll
        for (int i = 0; i < 4; ++i) {
            afr[0][i] = *(const bf16x8*)&L[db + arow0 + i * 1024 + col0];
            afr[1][i] = *(const bf16x8*)&L[db + arow0 + i * 1024 + col1];
            bfr[0][i] = *(const bf16x8*)&L[db + brow0 + i * 1024 + col0];
            bfr[1][i] = *(const bf16x8*)&L[db + brow0 + i * 1024 + col1];
        }
        __builtin_amdgcn_s_setprio(1);
#pragma unroll
        for (int ks = 0; ks < 2; ++ks)
#pragma unroll
            for (int im = 0; im < 4; ++im)
#pragma unroll
                for (int in = 0; in < 4; ++in)
                    acc[im][in] = __builtin_amdgcn_mfma_f32_16x16x32_bf16(
                        afr[ks][im], bfr[ks][in], acc[im][in], 0, 0, 0);
        __builtin_amdgcn_s_setprio(0);
        BAR();
        if (t + 2 < NT) { STAGE256(t + 2); WAIT_VM(6); }
        else WAIT_VM(0);
        BAR();
    }

    epi256<TO, MODE>(acc, L, bias, O0, O1, O2, N, m0, n0, tid);
}
#undef STAGE256

// Flash attention, causal, fixed-shift log2 softmax, P kept in REGISTERS.
// v5 = v3 (128 q-rows/block, 2 q-groups/wave, T14 reg-prefetch -- the proven
// ~71us structure) + K/V LDS DOUBLE-BUFFER (1 barrier/tile instead of 2:
// write buf[kt&1]; its last readers were tile kt-2, separated by the kt-1
// barrier -- hazard-free) + T5 setprio around both MFMA clusters.
__global__ __launch_bounds__(256, 3)
void attn_kernel(const bf16* __restrict__ Q, const bf16* __restrict__ K,
                 const bf16* __restrict__ Vt_g, bf16* __restrict__ ctx)
{
    const int jt = 15 - (blockIdx.x >> 6);   // Q-tile index (128 rows), heavy first
    const int bh = blockIdx.x & 63;
    const int b  = bh >> 4, h = bh & 15;
    const int q0 = jt * 128;
    const bf16* Qp = Q + (size_t)bh * NS * NHD;
    const bf16* Kp = K + (size_t)bh * NS * NHD;
    const bf16* Vp = Vt_g + (size_t)bh * NHD * NS;   // [hd][S]

    // dbuf K/V: 2 x (Kh 64x72 + Vh 64x72) = 36KB.  Q staging (128x72=18KB)
    // aliases buf0 (dead after qf extraction); O staging aliases at end.
    __shared__ union {
        struct { bf16 Kh[64 * 72]; bf16 Vh[64 * 72]; } s[2];
        bf16 QO[128 * 72];
    } u;

    const int tid  = threadIdx.x;
    const int lane = tid & 63;
    const int w    = tid >> 6;
    const int lr   = lane & 15, quad = lane >> 4;

    const int srow = tid >> 3;
    const int sch  = (tid & 7) * 8;

    // T14 prefetch registers: K/V tile in flight during compute
    bf16x8 kreg[2], vreg[2];
#pragma unroll
    for (int i = 0; i < 2; ++i) {
        kreg[i] = *(const bf16x8*)(Kp + (size_t)(srow + 32 * i) * NHD + sch);
        vreg[i] = *(const bf16x8*)(Vp + (size_t)(srow + 32 * i) * NS + sch);
    }

    // stage Q while the kt=0 K/V loads are in flight
#pragma unroll
    for (int i = 0; i < 4; ++i) {
        int row = srow + 32 * i;
        *(bf16x8*)(&u.QO[sw(row, sch)]) =
            *(const bf16x8*)(Qp + (size_t)(q0 + row) * NHD + sch);
    }
    __syncthreads();

    // hoist Q-fragments (k-loop invariant): qf[qg][ks]
    bf16x8 qf[2][2];
#pragma unroll
    for (int qg = 0; qg < 2; ++qg)
#pragma unroll
        for (int ks = 0; ks < 2; ++ks)
            qf[qg][ks] = *(const bf16x8*)(&u.QO[sw(w * 32 + qg * 16 + lr, ks * 32 + quad * 8)]);
    __syncthreads();   // QO region dead; Kh/Vh writes may begin

    float l_part[2] = {0.f, 0.f};
    f32x4 acco[2][4] = {};           // O^T per qg: hd = jn*16+quad*4+r, col = q

    const int wq0 = q0 + w * 32;     // this wave's first q row
    const int nkt = 2 * jt + 2;
    for (int kt = 0; kt < nkt; ++kt) {
        bf16* Kh = u.s[kt & 1].Kh;
        bf16* Vh = u.s[kt & 1].Vh;
        // reg -> LDS buf[kt&1] (vmcnt waited via register dep)
#pragma unroll
        for (int i = 0; i < 2; ++i) {
            *(bf16x8*)(&Kh[sw(srow + 32 * i, sch)]) = kreg[i];
            *(bf16x8*)(&Vh[sw(srow + 32 * i, sch)]) = vreg[i];
        }
        // issue next tile's global loads; land during compute below
        if (kt + 1 < nkt) {
#pragma unroll
            for (int i = 0; i < 2; ++i) {
                kreg[i] = *(const bf16x8*)(Kp + (size_t)((kt + 1) * 64 + srow + 32 * i) * NHD + sch);
                vreg[i] = *(const bf16x8*)(Vp + (size_t)(srow + 32 * i) * NS + (kt + 1) * 64 + sch);
            }
        }
        __syncthreads();   // buf[kt&1] ready; ONLY barrier in the tile

        if (kt * 64 <= wq0 + 31) {
            // S^T = K @ Q^T: one K-frag read feeds BOTH q-groups
            f32x4 sacc[2][4] = {};
#pragma unroll
            for (int ks = 0; ks < 2; ++ks) {
#pragma unroll
                for (int kn = 0; kn < 4; ++kn) {
                    bf16x8 ak = *(const bf16x8*)(&Kh[sw(kn * 16 + lr, ks * 32 + quad * 8)]);
                    __builtin_amdgcn_s_setprio(1);
                    sacc[0][kn] = __builtin_amdgcn_mfma_f32_16x16x32_bf16(ak, qf[0][ks], sacc[0][kn], 0, 0, 0);
                    sacc[1][kn] = __builtin_amdgcn_mfma_f32_16x16x32_bf16(ak, qf[1][ks], sacc[1][kn], 0, 0, 0);
                    __builtin_amdgcn_s_setprio(0);
                }
            }

            // softmax in registers; p-values land directly in x16 B-frag layout
            const bool diag = (kt * 64 + 63 > wq0);
            bf16x4 pf[2][4];
#pragma unroll
            for (int qg = 0; qg < 2; ++qg) {
                const int qrow = wq0 + qg * 16 + lr;
#pragma unroll
                for (int kn = 0; kn < 4; ++kn) {
#pragma unroll
                    for (int r = 0; r < 4; ++r) {
                        float x = sacc[qg][kn][r];
                        if (diag) {
                            int kcol = kt * 64 + kn * 16 + quad * 4 + r;
                            x = (kcol <= qrow) ? x : -INFINITY;
                        }
                        float p = __builtin_amdgcn_exp2f(x - FMAX);  // -inf -> 0
                        l_part[qg] += p;
                        pf[qg][kn][r] = (bf16)p;
                    }
                }
            }

            // O^T += V^T @ P^T: one V-frag read feeds BOTH q-groups
#pragma unroll
            for (int kn = 0; kn < 4; ++kn) {
#pragma unroll
                for (int jn = 0; jn < 4; ++jn) {
                    bf16x4 av = *(const bf16x4*)(&Vh[sw(jn * 16 + lr, kn * 16 + quad * 4)]);
                    __builtin_amdgcn_s_setprio(1);
                    acco[0][jn] = mfma16(av, pf[0][kn], acco[0][jn]);
                    acco[1][jn] = mfma16(av, pf[1][kn], acco[1][jn]);
                    __builtin_amdgcn_s_setprio(0);
                }
            }
        }
        // no trailing barrier: next write targets buf[(kt+1)&1], last read at
        // kt-1 and fenced by THIS tile's barrier on the following iteration
    }

    // l lives per-lane (one qrow per lane per qg); reduce across the 4 quads
    float rinv[2];
#pragma unroll
    for (int qg = 0; qg < 2; ++qg) {
        float l = l_part[qg];
        l += __shfl_xor(l, 16);
        l += __shfl_xor(l, 32);
        rinv[qg] = 1.0f / l;
    }

    // epilogue: O^T -> QO (dead) as packed b64 rows, then coalesced b128 out
    __syncthreads();
#pragma unroll
    for (int qg = 0; qg < 2; ++qg)
#pragma unroll
        for (int jn = 0; jn < 4; ++jn) {
            bf16x4 pv;
#pragma unroll
            for (int r = 0; r < 4; ++r) pv[r] = (bf16)(acco[qg][jn][r] * rinv[qg]);
            *(bf16x4*)&u.QO[(w * 32 + qg * 16 + lr) * 72 + jn * 16 + quad * 4] = pv;
        }
    __syncthreads();
#pragma unroll
    for (int p = 0; p < 4; ++p) {
        int idx = tid + 256 * p;
        int row = idx >> 3, colg = (idx & 7) * 8;
        bf16x8 v8 = *(const bf16x8*)&u.QO[row * 72 + colg];
        *(bf16x8*)&ctx[((size_t)(b * NS) + q0 + row) * ND + h * NHD + colg] = v8;
    }
}

extern "C" void kernel_launch(void* const* d_in, const int* in_sizes, int n_in,
                              void* d_out, int out_size, void* d_ws, size_t ws_size,
                              hipStream_t stream) {
    const float* x     = (const float*)d_in[0];
    const float* Wqkv  = (const float*)d_in[1];
    const float* bqkv  = (const float*)d_in[2];
    const float* Wproj = (const float*)d_in[3];
    const float* bproj = (const float*)d_in[4];
    float* out = (float*)d_out;

    const size_t per = (size_t)NB * NH * NS * NHD;  // 8,388,608 elems
    bf16* q_ws = (bf16*)d_ws;
    bf16* k_ws = q_ws + per;
    bf16* v_ws = k_ws + per;        // V transposed [B,H,HD,S]
    bf16* x_bf = v_ws + per;        // x as bf16; reused as ctx after QKV GEMM
    bf16* c_ws = x_bf;              // alias: x_bf dead once QKV GEMM completes
    bf16* wq_bf = x_bf + per;       // Wqkv bf16
    bf16* wp_bf = wq_bf + (size_t)3 * ND * ND;  // Wproj bf16

    const int n0 = NB * NS * ND;        // 8,388,608
    const int n1 = 3 * ND * ND;         // 3,145,728
    const int n2 = ND * ND;             // 1,048,576
    convert_kernel<<<(n0 + n1 + n2) / (256 * 8), 256, 0, stream>>>(
        x, x_bf, n0, Wqkv, wq_bf, n1, Wproj, wp_bf, n2);

    // QKV: 128x256 tiles -> grid 12x64 = 768 blocks = 3/CU (proven 2-phase)
    dim3 gq(3 * ND / 256, NB * NS / 128);
    gemm256<bf16, 0><<<gq, 512, 0, stream>>>(
        x_bf, wq_bf, bqkv, v_ws, q_ws, k_ws, 3 * ND, ND);

    // attn: 128 q-rows/block -> 16 jt x 64 bh = 1024 blocks = 4/CU supply
    attn_kernel<<<dim3(NB * NH * 16), 256, 0, stream>>>(q_ws, k_ws, v_ws, c_ws);

    // proj: 128x256 tiles -> grid 4x64 = 256 blocks = exactly 1/CU (2-phase)
    dim3 gp(ND / 256, NB * NS / 128);
    gemm256<float, 1><<<gp, 512, 0, stream>>>(
        c_ws, wp_bf, bproj, out, nullptr, nullptr, ND, ND);
}